// Round 6
// baseline (180.497 us; speedup 1.0000x reference)
//
#include <hip/hip_runtime.h>

// ExpertCompoundTracker: MoE load-EMA + pairwise co-activation histogram.
// Inputs: expert_indices [N,K] int32, expert_weights (UNUSED),
//         expert_load_ema [E] f32, expert_pair_coactivation [E,E] f32.
// Outputs concat: new_load_ema [64] then new_coact [4096], f32.
//
// R6 = R5's accum (512x512, 8 tokens/thread, all loads batched ahead of use,
// sched_barrier(0) pin — proven 4 waves/SIMD shape) + fused last-block-done
// finalize. R3/R4's fused-version regressions are explained by their bad
// load/wave shape (VGPR=16/20 -> serialized loads, 2 waves/SIMD), not the
// fence; this round isolates that: R5 structure +/- fusion only.

#define N_TOKENS    2097152
#define NUM_EXPERTS 64
#define NCELLS      (NUM_EXPERTS * NUM_EXPERTS)  // 4096
#define NBLOCKS     512
#define NTHREADS    512
#define STRIDE      (NBLOCKS * NTHREADS)         // 262144 threads -> 8 tokens each

__device__ __forceinline__ void pair_add(int* s, int a, int b) {
    const int lo = min(a, b), hi = max(a, b);
    // bijective swizzle: bank = (hi%32) ^ (lo&31) -> uniform
    atomicAdd(&s[(lo << 6) + (hi ^ (lo & 31))], 1);
}

__device__ __forceinline__ void token_add(int* s, int4 v) {
    pair_add(s, v.x, v.y);
    pair_add(s, v.x, v.z);
    pair_add(s, v.x, v.w);
    pair_add(s, v.y, v.z);
    pair_add(s, v.y, v.w);
    pair_add(s, v.z, v.w);
}

__device__ __forceinline__ int ws_load(int* p) {
    // agent-scope load: coherent view of device-scope atomic results
    return __hip_atomic_load(p, __ATOMIC_RELAXED, __HIP_MEMORY_SCOPE_AGENT);
}

__global__ __launch_bounds__(NTHREADS) void coact_fused_kernel(
    const int* __restrict__ idx,
    const float* __restrict__ ema_in,
    const float* __restrict__ coact_in,
    int* __restrict__ ws,            // [NCELLS] histogram + [1] done-counter
    float* __restrict__ out)
{
    __shared__ int s_coact[NCELLS];  // 16 KB, swizzled upper-triangle cells
    __shared__ int s_last;
    for (int i = threadIdx.x; i < NCELLS; i += NTHREADS) s_coact[i] = 0;
    __syncthreads();

    const int tid = blockIdx.x * NTHREADS + threadIdx.x;
    const int4* __restrict__ idx4 = (const int4*)idx;

    // Phase 1: all 8 independent global_load_dwordx4 in flight (4 KB/wave).
    int4 v[8];
    #pragma unroll
    for (int i = 0; i < 8; ++i) v[i] = idx4[tid + i * STRIDE];

    // Pin: one vmcnt drain instead of 8 serial ~700-cycle round-trips
    // (R3/R4 showed the compiler re-serializes to save VGPRs otherwise).
    __builtin_amdgcn_sched_barrier(0);

    // Phase 2: 48 fire-and-forget LDS atomics.
    #pragma unroll
    for (int i = 0; i < 8; ++i) token_add(s_coact, v[i]);

    __syncthreads();

    // Flush: unswizzle, skip always-zero lower-triangle cells (~2080/block).
    for (int i = threadIdx.x; i < NCELLS; i += NTHREADS) {
        int c = s_coact[i];
        if (c) {
            const int lo = i >> 6;
            const int hi = (i & 63) ^ (lo & 31);
            atomicAdd(&ws[(lo << 6) + hi], c);
        }
    }

    // Last-block-done: release fence + device-scope counter.
    __threadfence();
    if (threadIdx.x == 0) {
        s_last = (atomicAdd(&ws[NCELLS], 1) == NBLOCKS - 1) ? 1 : 0;
    }
    __syncthreads();
    if (!s_last) return;

    __threadfence();  // acquire side

    // new_coact: mirror upper-triangle ws (diagonal x2 — reference adds
    // .at[a,b] and .at[b,a]). ws is L2-warm from our own flush.
    for (int c = threadIdx.x; c < NCELLS; c += NTHREADS) {
        const int i = c >> 6, j = c & 63;
        const int lo = min(i, j), hi = max(i, j);
        int d = ws_load(&ws[(lo << 6) + hi]);
        if (i == j) d *= 2;
        out[NUM_EXPERTS + c] = coact_in[c] + (float)d;
    }

    // counts[e] = rowsum(sym delta)/3 exactly (each occurrence of e pairs
    // with the other 3 slots, duplicates included).
    if (threadIdx.x < NUM_EXPERTS) {
        const int t = threadIdx.x;
        int rowsum = 0;
        #pragma unroll
        for (int j = 0; j < NUM_EXPERTS; ++j) {
            const int lo = min(t, j), hi = max(t, j);
            int d = ws_load(&ws[(lo << 6) + hi]);
            rowsum += (j == t) ? 2 * d : d;
        }
        const int count = rowsum / 3;
        const float load = (float)count / (float)N_TOKENS;
        out[t] = ema_in[t] * 0.99f + load * 0.01f;
    }
}

extern "C" void kernel_launch(void* const* d_in, const int* in_sizes, int n_in,
                              void* d_out, int out_size, void* d_ws, size_t ws_size,
                              hipStream_t stream)
{
    const int*   idx      = (const int*)d_in[0];
    // d_in[1] = expert_weights: unused by the reference -> never read.
    const float* ema_in   = (const float*)d_in[2];
    const float* coact_in = (const float*)d_in[3];
    float*       out      = (float*)d_out;
    int*         ws       = (int*)d_ws;

    // Zero histogram + done-counter (ws is re-poisoned 0xAA each iteration).
    hipMemsetAsync(ws, 0, (NCELLS + 1) * sizeof(int), stream);

    coact_fused_kernel<<<NBLOCKS, NTHREADS, 0, stream>>>(idx, ema_in, coact_in, ws, out);
}

// Round 7
// 102.717 us; speedup vs baseline: 1.7572x; 1.7572x over previous
//
#include <hip/hip_runtime.h>

// ExpertCompoundTracker: MoE load-EMA + pairwise co-activation histogram.
// Inputs: expert_indices [N,K] int32, expert_weights (UNUSED),
//         expert_load_ema [E] f32, expert_pair_coactivation [E,E] f32.
// Outputs concat: new_load_ema [64] then new_coact [4096], f32.
//
// R7: 2 dispatches, zero global atomics, no memset, no fences.
//  - R6 proved per-block device-scope __threadfence costs tens of us on
//    gfx950 (cross-XCD L2 wb/inv) -> fusion is off the table for good.
//  - accum: R5's proven shape (512x512, 8 tokens/thread batched ahead of
//    use, sched_barrier pin) but flushes via PLAIN STORES to a private
//    ws slice (4096 swizzled cells + 64 block-local rowsums). Write-before-
//    read => no pre-zeroing of ws needed => memset dispatch eliminated.
//  - finalize: 64 blocks; block b reduces row b over 512 slices (coalesced),
//    writes sym row+col (each out cell exactly once), and reduces the 512
//    slice-rowsums for expert b's EMA (rowsum == 3*count identity, R1-verified).

#define N_TOKENS    2097152
#define NUM_EXPERTS 64
#define NCELLS      (NUM_EXPERTS * NUM_EXPERTS)  // 4096
#define NBLOCKS     512
#define NTHREADS    512
#define STRIDE      (NBLOCKS * NTHREADS)         // 262144 threads -> 8 tokens each
#define SLICE       (NCELLS + NUM_EXPERTS)       // 4160 ints per block slice (16B-aligned)

__device__ __forceinline__ void pair_add(int* s, int a, int b) {
    const int lo = min(a, b), hi = max(a, b);
    // bijective in-row swizzle: bank = (hi%32) ^ (lo&31) -> uniform
    atomicAdd(&s[(lo << 6) + (hi ^ (lo & 31))], 1);
}

__device__ __forceinline__ void token_add(int* s, int4 v) {
    pair_add(s, v.x, v.y);
    pair_add(s, v.x, v.z);
    pair_add(s, v.x, v.w);
    pair_add(s, v.y, v.z);
    pair_add(s, v.y, v.w);
    pair_add(s, v.z, v.w);
}

__global__ __launch_bounds__(NTHREADS) void coact_accum_kernel(
    const int* __restrict__ idx, int* __restrict__ ws)
{
    __shared__ int s_coact[NCELLS];   // 16 KB, swizzled upper-triangle cells
    __shared__ int s_row[NUM_EXPERTS];
    for (int i = threadIdx.x; i < NCELLS; i += NTHREADS) s_coact[i] = 0;
    if (threadIdx.x < NUM_EXPERTS) s_row[threadIdx.x] = 0;
    __syncthreads();

    const int tid = blockIdx.x * NTHREADS + threadIdx.x;
    const int4* __restrict__ idx4 = (const int4*)idx;

    // All 8 independent global_load_dwordx4 in flight (4 KB/wave), then one
    // vmcnt drain (R3/R4: compiler re-serializes to save VGPRs if allowed).
    int4 v[8];
    #pragma unroll
    for (int i = 0; i < 8; ++i) v[i] = idx4[tid + i * STRIDE];
    __builtin_amdgcn_sched_barrier(0);

    #pragma unroll
    for (int i = 0; i < 8; ++i) token_add(s_coact, v[i]);

    __syncthreads();

    // Block-local rowsum_e = sum_{j>e} U[e][j] + 2*U[e][e] + sum_{j<e} U[j][e]
    // (equals 3 * block-local count[e]; summed across blocks in finalize).
    {
        const int e = threadIdx.x & 63;
        const int c = threadIdx.x >> 6;            // 8 chunks of 8 columns
        int p = 0;
        #pragma unroll
        for (int k = 0; k < 8; ++k) {
            const int j = c * 8 + k;
            int u;
            if (j >= e) {
                u = s_coact[(e << 6) + (j ^ (e & 31))];
                if (j == e) u <<= 1;               // diagonal counts twice
            } else {
                u = s_coact[(j << 6) + (e ^ (j & 31))];
            }
            p += u;
        }
        atomicAdd(&s_row[e], p);
    }
    __syncthreads();

    // Plain-store the slice: no pre-zero needed, no global atomics.
    int* slice = ws + blockIdx.x * SLICE;
    const int4* sc4 = (const int4*)s_coact;
    int4* dst4 = (int4*)slice;
    dst4[threadIdx.x * 2]     = sc4[threadIdx.x * 2];
    dst4[threadIdx.x * 2 + 1] = sc4[threadIdx.x * 2 + 1];
    if (threadIdx.x < NUM_EXPERTS / 4) {
        ((int4*)(slice + NCELLS))[threadIdx.x] = ((const int4*)s_row)[threadIdx.x];
    }
}

__global__ __launch_bounds__(512) void finalize_kernel(
    const int* __restrict__ ws,
    const float* __restrict__ ema_in,
    const float* __restrict__ coact_in,
    float* __restrict__ out)
{
    __shared__ int red[512];
    __shared__ int rowf[NUM_EXPERTS];
    __shared__ int s_rowsum;
    const int b = blockIdx.x;       // expert / matrix row
    const int t = threadIdx.x;
    if (t == 0) s_rowsum = 0;

    // EMA partial: one slice-rowsum per thread (independent, issued early).
    const int ema_part = ws[t * SLICE + NCELLS + b];

    // Reduce swizzled row b over 512 slices: lane-consecutive -> coalesced.
    const int g = t >> 6, lane = t & 63;
    int acc = 0;
    #pragma unroll 8
    for (int s = g * 64; s < g * 64 + 64; ++s)
        acc += ws[s * SLICE + b * 64 + lane];
    red[t] = acc;
    __syncthreads();                 // also orders s_rowsum init before atomics

    if (t < NUM_EXPERTS) {
        int v = 0;
        #pragma unroll
        for (int gg = 0; gg < 8; ++gg) v += red[gg * 64 + t];
        rowf[t] = v;                 // rowf[pos] = U[b][hi] at pos = hi^(b&31)
    }
    atomicAdd(&s_rowsum, ema_part);
    __syncthreads();

    // Write symmetric outputs: block b owns row b (j>=b) and column b (j>b).
    if (t < NUM_EXPERTS) {
        const int j = t;
        if (j > b) {
            const float d = (float)rowf[j ^ (b & 31)];
            out[NUM_EXPERTS + b * 64 + j] = coact_in[b * 64 + j] + d;
            out[NUM_EXPERTS + j * 64 + b] = coact_in[j * 64 + b] + d;
        } else if (j == b) {
            out[NUM_EXPERTS + b * 65] =
                coact_in[b * 65] + 2.0f * (float)rowf[b ^ (b & 31)];
        }
    }
    if (t == 0) {
        const int count = s_rowsum / 3;   // exact: rowsum == 3*count
        const float load = (float)count / (float)N_TOKENS;
        out[b] = ema_in[b] * 0.99f + load * 0.01f;
    }
}

extern "C" void kernel_launch(void* const* d_in, const int* in_sizes, int n_in,
                              void* d_out, int out_size, void* d_ws, size_t ws_size,
                              hipStream_t stream)
{
    const int*   idx      = (const int*)d_in[0];
    // d_in[1] = expert_weights: unused by the reference -> never read.
    const float* ema_in   = (const float*)d_in[2];
    const float* coact_in = (const float*)d_in[3];
    float*       out      = (float*)d_out;
    int*         ws       = (int*)d_ws;   // 512 slices x 4160 ints = 8.5 MB, write-before-read

    coact_accum_kernel<<<NBLOCKS, NTHREADS, 0, stream>>>(idx, ws);
    finalize_kernel<<<NUM_EXPERTS, 512, 0, stream>>>(ws, ema_in, coact_in, out);
}

// Round 8
// 99.025 us; speedup vs baseline: 1.8227x; 1.0373x over previous
//
#include <hip/hip_runtime.h>

// ExpertCompoundTracker: MoE load-EMA + pairwise co-activation histogram.
// Inputs: expert_indices [N,K] int32, expert_weights (UNUSED),
//         expert_load_ema [E] f32, expert_pair_coactivation [E,E] f32.
// Outputs concat: new_load_ema [64] then new_coact [4096], f32.
//
// R8 = R7 with halved slice count: 256 blocks x 1024 threads (same 16
// waves/CU, 4/SIMD as R7's 2x512 — the proven latency-hiding shape), so
// slice traffic drops 8.5 -> 4.25 MB on both the accum-write and the
// finalize-read side. LDS init vectorized; slice store = 1 int4/thread.
// Keeps: plain-store slices (no ws pre-zero, no global atomics), batched
// loads + sched_barrier pin, no fences (R6: per-block device fence is
// catastrophic on non-coherent XCD L2s), rowsum==3*count EMA identity.

#define N_TOKENS    2097152
#define NUM_EXPERTS 64
#define NCELLS      (NUM_EXPERTS * NUM_EXPERTS)  // 4096
#define NBLOCKS     256
#define NTHREADS    1024
#define STRIDE      (NBLOCKS * NTHREADS)         // 262144 threads -> 8 tokens each
#define SLICE       (NCELLS + NUM_EXPERTS)       // 4160 ints per block slice (16B-aligned)

__device__ __forceinline__ void pair_add(int* s, int a, int b) {
    const int lo = min(a, b), hi = max(a, b);
    // bijective in-row swizzle: bank = (hi%32) ^ (lo&31) -> uniform
    atomicAdd(&s[(lo << 6) + (hi ^ (lo & 31))], 1);
}

__device__ __forceinline__ void token_add(int* s, int4 v) {
    pair_add(s, v.x, v.y);
    pair_add(s, v.x, v.z);
    pair_add(s, v.x, v.w);
    pair_add(s, v.y, v.z);
    pair_add(s, v.y, v.w);
    pair_add(s, v.z, v.w);
}

__global__ __launch_bounds__(NTHREADS) void coact_accum_kernel(
    const int* __restrict__ idx, int* __restrict__ ws)
{
    __shared__ int s_coact[NCELLS];   // 16 KB, swizzled upper-triangle cells
    __shared__ int s_row[NUM_EXPERTS];
    // Vectorized zero-init: 1 int4 per thread.
    ((int4*)s_coact)[threadIdx.x] = make_int4(0, 0, 0, 0);
    if (threadIdx.x < NUM_EXPERTS) s_row[threadIdx.x] = 0;
    __syncthreads();

    const int tid = blockIdx.x * NTHREADS + threadIdx.x;
    const int4* __restrict__ idx4 = (const int4*)idx;

    // All 8 independent global_load_dwordx4 in flight (4 KB/wave), then one
    // vmcnt drain (R3/R4: compiler re-serializes to save VGPRs if allowed).
    int4 v[8];
    #pragma unroll
    for (int i = 0; i < 8; ++i) v[i] = idx4[tid + i * STRIDE];
    __builtin_amdgcn_sched_barrier(0);

    #pragma unroll
    for (int i = 0; i < 8; ++i) token_add(s_coact, v[i]);

    __syncthreads();

    // Block-local rowsum_e = sum_{j>e} U[e][j] + 2*U[e][e] + sum_{j<e} U[j][e]
    // (== 3 * block-local count[e]; summed across slices in finalize).
    {
        const int e = threadIdx.x & 63;
        const int c = threadIdx.x >> 6;            // 16 chunks of 4 columns
        int p = 0;
        #pragma unroll
        for (int k = 0; k < 4; ++k) {
            const int j = c * 4 + k;
            int u;
            if (j >= e) {
                u = s_coact[(e << 6) + (j ^ (e & 31))];
                if (j == e) u <<= 1;               // diagonal counts twice
            } else {
                u = s_coact[(j << 6) + (e ^ (j & 31))];
            }
            p += u;
        }
        atomicAdd(&s_row[e], p);
    }
    __syncthreads();

    // Plain-store the slice: no pre-zero needed, no global atomics.
    int* slice = ws + blockIdx.x * SLICE;
    ((int4*)slice)[threadIdx.x] = ((const int4*)s_coact)[threadIdx.x];
    if (threadIdx.x < NUM_EXPERTS / 4) {
        ((int4*)(slice + NCELLS))[threadIdx.x] = ((const int4*)s_row)[threadIdx.x];
    }
}

__global__ __launch_bounds__(512) void finalize_kernel(
    const int* __restrict__ ws,
    const float* __restrict__ ema_in,
    const float* __restrict__ coact_in,
    float* __restrict__ out)
{
    __shared__ int red[512];
    __shared__ int rowf[NUM_EXPERTS];
    __shared__ int s_rowsum;
    const int b = blockIdx.x;       // expert / matrix row
    const int t = threadIdx.x;
    if (t == 0) s_rowsum = 0;

    // EMA partial: one slice-rowsum per thread for t < NBLOCKS.
    const int ema_part = (t < NBLOCKS) ? ws[t * SLICE + NCELLS + b] : 0;

    // Reduce swizzled row b over 256 slices: lane-consecutive -> coalesced.
    const int g = t >> 6, lane = t & 63;           // 8 lane-groups x 32 slices
    int acc = 0;
    #pragma unroll 8
    for (int s = g * 32; s < g * 32 + 32; ++s)
        acc += ws[s * SLICE + b * 64 + lane];
    red[t] = acc;
    __syncthreads();                 // also orders s_rowsum init before atomics

    if (t < NUM_EXPERTS) {
        int v = 0;
        #pragma unroll
        for (int gg = 0; gg < 8; ++gg) v += red[gg * 64 + t];
        rowf[t] = v;                 // rowf[pos] = U[b][hi] at pos = hi^(b&31)
    }
    if (t < NBLOCKS) atomicAdd(&s_rowsum, ema_part);
    __syncthreads();

    // Write symmetric outputs: block b owns row b (j>=b) and column b (j>b).
    if (t < NUM_EXPERTS) {
        const int j = t;
        if (j > b) {
            const float d = (float)rowf[j ^ (b & 31)];
            out[NUM_EXPERTS + b * 64 + j] = coact_in[b * 64 + j] + d;
            out[NUM_EXPERTS + j * 64 + b] = coact_in[j * 64 + b] + d;
        } else if (j == b) {
            out[NUM_EXPERTS + b * 65] =
                coact_in[b * 65] + 2.0f * (float)rowf[b ^ (b & 31)];
        }
    }
    if (t == 0) {
        const int count = s_rowsum / 3;   // exact: rowsum == 3*count
        const float load = (float)count / (float)N_TOKENS;
        out[b] = ema_in[b] * 0.99f + load * 0.01f;
    }
}

extern "C" void kernel_launch(void* const* d_in, const int* in_sizes, int n_in,
                              void* d_out, int out_size, void* d_ws, size_t ws_size,
                              hipStream_t stream)
{
    const int*   idx      = (const int*)d_in[0];
    // d_in[1] = expert_weights: unused by the reference -> never read.
    const float* ema_in   = (const float*)d_in[2];
    const float* coact_in = (const float*)d_in[3];
    float*       out      = (float*)d_out;
    int*         ws       = (int*)d_ws;   // 256 slices x 4160 ints = 4.25 MB, write-before-read

    coact_accum_kernel<<<NBLOCKS, NTHREADS, 0, stream>>>(idx, ws);
    finalize_kernel<<<NUM_EXPERTS, 512, 0, stream>>>(ws, ema_in, coact_in, out);
}